// Round 10
// baseline (190.074 us; speedup 1.0000x reference)
//
#include <hip/hip_runtime.h>
#include <hip/hip_bf16.h>

// Problem: M=8, B=4, S=512, D=512, H=8, HD=64.
// Pipeline: prep (xcast + wqkv^T + wproj^T fused) -> QKV GEMM (256x128, 3-buf
// counted-vmcnt, swizzle, setprio) -> paired-tile flash attention (3-buf
// counted-vmcnt, setprio) -> proj GEMM (128x128, 3-buf, setprio).

typedef unsigned short u16;
typedef unsigned int u32;
typedef __attribute__((ext_vector_type(8))) short short8;        // bf16x8 MFMA frag
typedef __attribute__((ext_vector_type(4))) float f32x4;         // MFMA acc frag
typedef __attribute__((ext_vector_type(4))) unsigned short u16x4;
typedef __attribute__((ext_vector_type(8))) unsigned short u16x8;
typedef __attribute__((ext_vector_type(2))) unsigned int u32x2;

#define MFMA16(a, b, c) __builtin_amdgcn_mfma_f32_16x16x32_bf16((a), (b), (c), 0, 0, 0)

__device__ __forceinline__ u16 f2bf(float f) {
  union { __hip_bfloat16 h; u16 u; } cv;
  cv.h = __float2bfloat16(f);
  return cv.u;
}

// async global->LDS, 16B per lane; lds base must be wave-uniform.
__device__ __forceinline__ void gl_lds16(const u16* g, u16* l) {
  __builtin_amdgcn_global_load_lds(
      (const __attribute__((address_space(1))) void*)g,
      (__attribute__((address_space(3))) void*)l, 16, 0, 0);
}

// ---------------------------------------------------------------------------
// Fused prep: blocks [0,1024) xcast; [1024,7168) wqkv^T; [7168,9216) wproj^T.
// ---------------------------------------------------------------------------
__global__ __launch_bounds__(256) void prep_kernel(const float* __restrict__ x,
                                                   u16* __restrict__ xb,
                                                   const float* __restrict__ wqkv,
                                                   u16* __restrict__ wqkvT,
                                                   const float* __restrict__ wproj,
                                                   u16* __restrict__ wprojT) {
  __shared__ float tsh[32][33];
  int bid = blockIdx.x;
  int t = threadIdx.x;
  if (bid < 1024) {
    const long n8 = (long)8 * 4 * 512 * 512 / 8;  // 1048576
    for (long i = (long)bid * 256 + t; i < n8; i += 1024L * 256) {
      f32x4 a = *(const f32x4*)(x + i * 8);
      f32x4 b = *(const f32x4*)(x + i * 8 + 4);
      u16x8 o = {f2bf(a[0]), f2bf(a[1]), f2bf(a[2]), f2bf(a[3]),
                 f2bf(b[0]), f2bf(b[1]), f2bf(b[2]), f2bf(b[3])};
      *(u16x8*)(xb + i * 8) = o;
    }
    return;
  }
  const float* pin;
  u16* pout;
  int R = 512, C, r0, c0;
  if (bid < 7168) {
    int id = bid - 1024;             // 6144 = 8 x 16 x 48
    int m = id / 768, rem = id % 768;
    int ry = rem / 48, cx = rem % 48;
    C = 1536; r0 = ry * 32; c0 = cx * 32;
    pin = wqkv + (size_t)m * 512 * 1536;
    pout = wqkvT + (size_t)m * 512 * 1536;
  } else {
    int id = bid - 7168;             // 2048 = 8 x 16 x 16
    int m = id / 256, rem = id % 256;
    int ry = rem / 16, cx = rem % 16;
    C = 512; r0 = ry * 32; c0 = cx * 32;
    pin = wproj + (size_t)m * 512 * 512;
    pout = wprojT + (size_t)m * 512 * 512;
  }
  int tx = t & 31, ty = t >> 5;  // (32, 8)
#pragma unroll
  for (int i = 0; i < 4; ++i) {
    int r = ty + i * 8;
    tsh[r][tx] = pin[(size_t)(r0 + r) * C + c0 + tx];
  }
  __syncthreads();
#pragma unroll
  for (int i = 0; i < 4; ++i) {
    int r = ty + i * 8;
    pout[(size_t)(c0 + r) * R + r0 + tx] = f2bf(tsh[tx][r]);
  }
}

// ---------------------------------------------------------------------------
// QKV GEMM: xb[m][2048][512] bf16 x wT[m][1536][512] bf16 -> scatter q/k/vT.
// 256x128 tile, BK=32, 8 waves. 3 LDS buffers, depth-2 counted vmcnt(3),
// one s_barrier per K-step, slot-XOR read swizzle, setprio around MFMA.
// Grid 768 1-D XCD-affine.
// ---------------------------------------------------------------------------
__global__ __launch_bounds__(512) void qkv_gemm_kernel(const u16* __restrict__ XB,
                                                       const u16* __restrict__ WT,
                                                       u16* __restrict__ Q,
                                                       u16* __restrict__ K,
                                                       u16* __restrict__ VT) {
  __shared__ __attribute__((aligned(16))) u16 As[3][256 * 32];  // 3 x 16 KB
  __shared__ __attribute__((aligned(16))) u16 Bs[3][128 * 32];  // 3 x 8 KB
  int bid = blockIdx.x;                     // 768 blocks
  int wgid = (bid & 7) * 96 + (bid >> 3);   // XCD-affine (768 % 8 == 0)
  int m = wgid / 96;
  int rem = wgid % 96;
  int r0 = (rem / 12) * 256, c0 = (rem % 12) * 128;
  const u16* A = XB + (size_t)m * 2048 * 512;
  const u16* BT = WT + (size_t)m * 1536 * 512;
  int t = threadIdx.x;
  int lane = t & 63, w = t >> 6;            // 8 waves
  int wr = (w >> 1) * 64, wc = (w & 1) * 64;
  int fr = lane & 15, fc = lane >> 4;

  int rA0 = t >> 2, sA0 = (t & 3) ^ ((rA0 >> 1) & 3);
  int rA1 = 128 + (t >> 2), sA1 = (t & 3) ^ ((rA1 >> 1) & 3);

  f32x4 acc[4][4];
#pragma unroll
  for (int i = 0; i < 4; ++i)
#pragma unroll
    for (int j = 0; j < 4; ++j) acc[i][j] = f32x4{0.f, 0.f, 0.f, 0.f};

#define QKV_STAGE(tile)                                                            \
  {                                                                                \
    int kk_ = (tile) * 32;                                                         \
    int b_ = (tile) % 3;                                                           \
    gl_lds16(A + (size_t)(r0 + rA0) * 512 + kk_ + sA0 * 8, &As[b_][w * 512]);      \
    gl_lds16(A + (size_t)(r0 + rA1) * 512 + kk_ + sA1 * 8, &As[b_][4096 + w * 512]); \
    gl_lds16(BT + (size_t)(c0 + rA0) * 512 + kk_ + sA0 * 8, &Bs[b_][w * 512]);     \
  }

#define QKV_COMPUTE(tile)                                                          \
  {                                                                                \
    int b_ = (tile) % 3;                                                           \
    short8 af[4], bf_[4];                                                          \
    _Pragma("unroll") for (int i = 0; i < 4; ++i) {                                \
      int row = wr + i * 16 + fr;                                                  \
      int sl = fc ^ ((row >> 1) & 3);                                              \
      af[i] = *(const short8*)&As[b_][row * 32 + sl * 8];                          \
    }                                                                              \
    _Pragma("unroll") for (int j = 0; j < 4; ++j) {                                \
      int row = wc + j * 16 + fr;                                                  \
      int sl = fc ^ ((row >> 1) & 3);                                              \
      bf_[j] = *(const short8*)&Bs[b_][row * 32 + sl * 8];                         \
    }                                                                              \
    __builtin_amdgcn_s_setprio(1);                                                 \
    _Pragma("unroll") for (int i = 0; i < 4; ++i)                                  \
      _Pragma("unroll") for (int j = 0; j < 4; ++j)                                \
        acc[i][j] = MFMA16(af[i], bf_[j], acc[i][j]);                              \
    __builtin_amdgcn_s_setprio(0);                                                 \
  }

  QKV_STAGE(0);
  QKV_STAGE(1);
  for (int ks = 0; ks < 14; ++ks) {
    asm volatile("s_waitcnt vmcnt(3)" ::: "memory");  // tile ks done; ks+1 in flight
    __builtin_amdgcn_sched_barrier(0);
    __builtin_amdgcn_s_barrier();
    QKV_STAGE(ks + 2);
    QKV_COMPUTE(ks);
    __builtin_amdgcn_sched_barrier(0);
  }
  asm volatile("s_waitcnt vmcnt(0)" ::: "memory");
  __builtin_amdgcn_sched_barrier(0);
  __builtin_amdgcn_s_barrier();
  QKV_COMPUTE(14);
  QKV_COMPUTE(15);

  int seg = c0 >> 9;  // uniform per block: 0=q, 1=k, 2=v
  if (seg == 2) {
#pragma unroll
    for (int i = 0; i < 4; ++i)
#pragma unroll
      for (int j = 0; j < 4; ++j) {
        int s0 = r0 + wr + i * 16 + fc * 4;
        int gcol = c0 + wc + j * 16 + fr;
        int cc = gcol & 511;
        int hh = cc >> 6, hd = cc & 63;
        int b = s0 >> 9, s = s0 & 511;
        size_t headoff = (size_t)((m * 4 + b) * 8 + hh) * 32768;
        u16x4 pk = {f2bf(acc[i][j][0]), f2bf(acc[i][j][1]),
                    f2bf(acc[i][j][2]), f2bf(acc[i][j][3])};
        *(u16x4*)(VT + headoff + (size_t)hd * 512 + s) = pk;
      }
  } else {
#pragma unroll
    for (int i = 0; i < 4; ++i)
#pragma unroll
      for (int j = 0; j < 4; ++j)
#pragma unroll
        for (int r = 0; r < 4; ++r) {
          int grow = r0 + wr + i * 16 + fc * 4 + r;
          int gcol = c0 + wc + j * 16 + fr;
          int b = grow >> 9, s = grow & 511;
          int cc = gcol & 511;
          int hh = cc >> 6, hd = cc & 63;
          size_t headoff = (size_t)((m * 4 + b) * 8 + hh) * 32768;
          u16 val = f2bf(acc[i][j][r]);
          if (seg == 0) Q[headoff + s * 64 + hd] = val;
          else          K[headoff + s * 64 + hd] = val;
        }
  }
}

// ---------------------------------------------------------------------------
// Flash attention, paired q-tiles, 3-buffer depth-2 counted-vmcnt pipeline.
// Grid 1024: bid>>8 = p (0..3), bid&255 = head. qtA=p, qtB=7-p. One s_barrier
// per k-tile; setprio around MFMA clusters.
// ---------------------------------------------------------------------------
__global__ __launch_bounds__(256) void attn_kernel(const u16* __restrict__ Qg,
                                                   const u16* __restrict__ Kg,
                                                   const u16* __restrict__ VTg,
                                                   u16* __restrict__ Yg) {
  __shared__ __attribute__((aligned(16))) u16 Ks[3][64 * 64];  // 3 x 8 KB
  __shared__ __attribute__((aligned(16))) u16 Vs[3][64 * 64];  // 3 x 8 KB
  __shared__ u16 Pl[4][16][72];
  int bid = blockIdx.x;
  int p = bid >> 8;
  int g = bid & 255;
  int h = g & 7, mb = g >> 3;
  int qtA = p, qtB = 7 - p;
  int t = threadIdx.x, lane = t & 63, w = t >> 6;
  int fr = lane & 15, fc = lane >> 4;
  size_t hoff = ((size_t)mb * 8 + h) * 32768;
  const u16* Q = Qg + hoff;
  const u16* K = Kg + hoff;
  const u16* V = VTg + hoff;  // [hd][s]
  const float SC = 0.125f * 1.44269504088896340736f;  // 1/sqrt(HD) * log2(e)

  int qrowA = qtA * 64 + w * 16 + fr;
  int qrowB = qtB * 64 + w * 16 + fr;
  short8 qA0 = *(const short8*)(Q + (size_t)qrowA * 64 + fc * 8);
  short8 qA1 = *(const short8*)(Q + (size_t)qrowA * 64 + 32 + fc * 8);
  short8 qB0 = *(const short8*)(Q + (size_t)qrowB * 64 + fc * 8);
  short8 qB1 = *(const short8*)(Q + (size_t)qrowB * 64 + 32 + fc * 8);

  f32x4 accA[4], accB[4];
#pragma unroll
  for (int d = 0; d < 4; ++d) {
    accA[d] = f32x4{0.f, 0.f, 0.f, 0.f};
    accB[d] = f32x4{0.f, 0.f, 0.f, 0.f};
  }
  float mstA = -1e30f, lstA = 0.f, mstB = -1e30f, lstB = 0.f;

  int sr0 = t >> 3, ss0 = (t & 7) ^ (sr0 & 7);
  int sr1 = 32 + (t >> 3), ss1 = (t & 7) ^ (sr1 & 7);

#define ATTN_STAGE(kt_, buf_)                                                     \
  {                                                                               \
    int kb_ = (kt_) * 64;                                                         \
    gl_lds16(K + (size_t)(kb_ + sr0) * 64 + ss0 * 8, &Ks[buf_][w * 512]);         \
    gl_lds16(K + (size_t)(kb_ + sr1) * 64 + ss1 * 8, &Ks[buf_][2048 + w * 512]);  \
    gl_lds16(V + (size_t)sr0 * 512 + kb_ + ss0 * 8, &Vs[buf_][w * 512]);          \
    gl_lds16(V + (size_t)sr1 * 512 + kb_ + ss1 * 8, &Vs[buf_][2048 + w * 512]);   \
  }

  int qloc = w * 16 + fr;
  ATTN_STAGE(0, 0);
  ATTN_STAGE(1, 1);
  int cur = 0;

  for (int kt = 0; kt <= qtB; ++kt) {
    if (kt < qtB) {
      asm volatile("s_waitcnt vmcnt(4)" ::: "memory");  // tile kt landed; kt+1 in flight
    } else {
      asm volatile("s_waitcnt vmcnt(0)" ::: "memory");
    }
    __builtin_amdgcn_sched_barrier(0);
    __builtin_amdgcn_s_barrier();  // DMA for buf cur landed; buf (kt+2)%3 reads done
    if (kt + 2 <= qtB) {
      int nb = (cur >= 1) ? cur - 1 : 2;  // (kt+2)%3
      ATTN_STAGE(kt + 2, nb);
    }

    auto tile_compute = [&](const short8& qf0, const short8& qf1, f32x4(&acc)[4],
                            float& mst, float& lst, bool diag) {
      f32x4 st[4];
      __builtin_amdgcn_s_setprio(1);
#pragma unroll
      for (int sub = 0; sub < 4; ++sub) {
        int row = sub * 16 + fr;
        short8 kf0 = *(const short8*)&Ks[cur][row * 64 + ((fc ^ (row & 7)) & 7) * 8];
        short8 kf1 = *(const short8*)&Ks[cur][row * 64 + (((4 + fc) ^ (row & 7)) & 7) * 8];
        f32x4 z = f32x4{0.f, 0.f, 0.f, 0.f};
        z = MFMA16(kf0, qf0, z);
        st[sub] = MFMA16(kf1, qf1, z);
      }
      __builtin_amdgcn_s_setprio(0);
      float pv[4][4];
      float mt = -3e30f;
#pragma unroll
      for (int sub = 0; sub < 4; ++sub)
#pragma unroll
        for (int r = 0; r < 4; ++r) {
          float v = st[sub][r] * SC;
          if (diag && (sub * 16 + fc * 4 + r) > qloc) v = -1e30f;
          pv[sub][r] = v;
          mt = fmaxf(mt, v);
        }
      mt = fmaxf(mt, __shfl_xor(mt, 16));
      mt = fmaxf(mt, __shfl_xor(mt, 32));
      float mn = fmaxf(mst, mt);
      float al = __builtin_amdgcn_exp2f(mst - mn);
      mst = mn;
      float rs = 0.f;
#pragma unroll
      for (int sub = 0; sub < 4; ++sub)
#pragma unroll
        for (int r = 0; r < 4; ++r) {
          float e = __builtin_amdgcn_exp2f(pv[sub][r] - mn);
          pv[sub][r] = e;
          rs += e;
        }
      rs += __shfl_xor(rs, 16);
      rs += __shfl_xor(rs, 32);
      lst = lst * al + rs;
#pragma unroll
      for (int d = 0; d < 4; ++d) acc[d] *= al;

#pragma unroll
      for (int sub = 0; sub < 4; ++sub) {
        u32 lo = (u32)f2bf(pv[sub][0]) | ((u32)f2bf(pv[sub][1]) << 16);
        u32 hi = (u32)f2bf(pv[sub][2]) | ((u32)f2bf(pv[sub][3]) << 16);
        *(u32x2*)&Pl[w][fr][sub * 16 + fc * 4] = u32x2{lo, hi};
      }
      __builtin_amdgcn_s_setprio(1);
#pragma unroll
      for (int dt = 0; dt < 4; ++dt)
#pragma unroll
        for (int kc = 0; kc < 2; ++kc) {
          int row = dt * 16 + fr;
          short8 vf = *(const short8*)&Vs[cur][row * 64 + (((kc * 4 + fc) ^ (row & 7)) & 7) * 8];
          short8 pb = *(const short8*)&Pl[w][fr][kc * 32 + fc * 8];
          acc[dt] = MFMA16(vf, pb, acc[dt]);
        }
      __builtin_amdgcn_s_setprio(0);
    };

    if (kt <= qtA) tile_compute(qA0, qA1, accA, mstA, lstA, kt == qtA);
    tile_compute(qB0, qB1, accB, mstB, lstB, kt == qtB);

    __builtin_amdgcn_sched_barrier(0);  // keep this iteration's reads before next barrier
    cur = (cur == 2) ? 0 : cur + 1;
  }

  float invA = 1.0f / lstA, invB = 1.0f / lstB;
#pragma unroll
  for (int dt = 0; dt < 4; ++dt) {
    u16x4 oA = {f2bf(accA[dt][0] * invA), f2bf(accA[dt][1] * invA),
                f2bf(accA[dt][2] * invA), f2bf(accA[dt][3] * invA)};
    *(u16x4*)(Yg + ((size_t)mb * 512 + qrowA) * 512 + h * 64 + dt * 16 + fc * 4) = oA;
    u16x4 oB = {f2bf(accB[dt][0] * invB), f2bf(accB[dt][1] * invB),
                f2bf(accB[dt][2] * invB), f2bf(accB[dt][3] * invB)};
    *(u16x4*)(Yg + ((size_t)mb * 512 + qrowB) * 512 + h * 64 + dt * 16 + fc * 4) = oB;
  }
}

// ---------------------------------------------------------------------------
// Projection GEMM: y[m][2048][512] bf16 x projT[m][512][512] -> out fp32.
// 128x128 tile (512 blocks = 2/CU), 3-buffer depth-2 counted vmcnt(4),
// slot-XOR swizzle, setprio. XCD-affine.
// ---------------------------------------------------------------------------
__global__ __launch_bounds__(256) void proj_gemm_kernel(const u16* __restrict__ Y,
                                                        const u16* __restrict__ PT,
                                                        float* __restrict__ OUT) {
  __shared__ __attribute__((aligned(16))) u16 As[3][128 * 32];
  __shared__ __attribute__((aligned(16))) u16 Bs[3][128 * 32];
  int bid = blockIdx.x;                    // 512 blocks
  int wgid = (bid & 7) * 64 + (bid >> 3);  // XCD-affine
  int m = wgid / 64;
  int rem = wgid % 64;
  int r0 = (rem / 4) * 128, c0 = (rem % 4) * 128;
  const u16* A = Y + (size_t)m * 2048 * 512;
  const u16* BT = PT + (size_t)m * 512 * 512;
  float* C = OUT + (size_t)m * 2048 * 512;
  int t = threadIdx.x;
  int lane = t & 63, w = t >> 6;
  int wr = (w >> 1) * 64, wc = (w & 1) * 64;
  int fr = lane & 15, fc = lane >> 4;

  int rA0 = t >> 2, sA0 = (t & 3) ^ ((rA0 >> 1) & 3);
  int rA1 = (t + 256) >> 2, sA1 = (t & 3) ^ ((rA1 >> 1) & 3);

  f32x4 acc[4][4];
#pragma unroll
  for (int i = 0; i < 4; ++i)
#pragma unroll
    for (int j = 0; j < 4; ++j) acc[i][j] = f32x4{0.f, 0.f, 0.f, 0.f};

#define PROJ_STAGE(tile)                                                           \
  {                                                                                \
    int kk_ = (tile) * 32;                                                         \
    int b_ = (tile) % 3;                                                           \
    gl_lds16(A + (size_t)(r0 + rA0) * 512 + kk_ + sA0 * 8, &As[b_][w * 512]);      \
    gl_lds16(A + (size_t)(r0 + rA1) * 512 + kk_ + sA1 * 8, &As[b_][2048 + w * 512]); \
    gl_lds16(BT + (size_t)(c0 + rA0) * 512 + kk_ + sA0 * 8, &Bs[b_][w * 512]);     \
    gl_lds16(BT + (size_t)(c0 + rA1) * 512 + kk_ + sA1 * 8, &Bs[b_][2048 + w * 512]); \
  }

#define PROJ_COMPUTE(tile)                                                         \
  {                                                                                \
    int b_ = (tile) % 3;                                                           \
    short8 af[4], bf_[4];                                                          \
    _Pragma("unroll") for (int i = 0; i < 4; ++i) {                                \
      int row = wr + i * 16 + fr;                                                  \
      int sl = fc ^ ((row >> 1) & 3);                                              \
      af[i] = *(const short8*)&As[b_][row * 32 + sl * 8];                          \
    }                                                                              \
    _Pragma("unroll") for (int j = 0; j < 4; ++j) {                                \
      int row = wc + j * 16 + fr;                                                  \
      int sl = fc ^ ((row >> 1) & 3);                                              \
      bf_[j] = *(const short8*)&Bs[b_][row * 32 + sl * 8];                         \
    }                                                                              \
    __builtin_amdgcn_s_setprio(1);                                                 \
    _Pragma("unroll") for (int i = 0; i < 4; ++i)                                  \
      _Pragma("unroll") for (int j = 0; j < 4; ++j)                                \
        acc[i][j] = MFMA16(af[i], bf_[j], acc[i][j]);                              \
    __builtin_amdgcn_s_setprio(0);                                                 \
  }

  PROJ_STAGE(0);
  PROJ_STAGE(1);
  for (int ks = 0; ks < 14; ++ks) {
    asm volatile("s_waitcnt vmcnt(4)" ::: "memory");
    __builtin_amdgcn_sched_barrier(0);
    __builtin_amdgcn_s_barrier();
    PROJ_STAGE(ks + 2);
    PROJ_COMPUTE(ks);
    __builtin_amdgcn_sched_barrier(0);
  }
  asm volatile("s_waitcnt vmcnt(0)" ::: "memory");
  __builtin_amdgcn_sched_barrier(0);
  __builtin_amdgcn_s_barrier();
  PROJ_COMPUTE(14);
  PROJ_COMPUTE(15);

#pragma unroll
  for (int i = 0; i < 4; ++i)
#pragma unroll
    for (int j = 0; j < 4; ++j)
#pragma unroll
      for (int r = 0; r < 4; ++r) {
        int grow = r0 + wr + i * 16 + fc * 4 + r;
        int gcol = c0 + wc + j * 16 + fr;
        C[(size_t)grow * 512 + gcol] = acc[i][j][r];
      }
}

// ---------------------------------------------------------------------------
extern "C" void kernel_launch(void* const* d_in, const int* in_sizes, int n_in,
                              void* d_out, int out_size, void* d_ws, size_t ws_size,
                              hipStream_t stream) {
  const float* x = (const float*)d_in[0];      // [8][4][512][512]
  const float* wqkv = (const float*)d_in[1];   // [8][512][1536]
  const float* wproj = (const float*)d_in[2];  // [8][512][512]
  float* out = (float*)d_out;                  // [8][4][512][512]

  u16* p = (u16*)d_ws;
  u16* wqkvT = p;  p += (size_t)8 * 1536 * 512;  // bf16 [m][1536][512]
  u16* wprojT = p; p += (size_t)8 * 512 * 512;   // bf16 [m][512][512]
  u16* qb = p;     p += (size_t)8388608;         // bf16 [mb*8+h][512][64]
  u16* kb = p;     p += (size_t)8388608;         // bf16 [mb*8+h][512][64]
  u16* vtb = p;    p += (size_t)8388608;         // bf16 [mb*8+h][64][512]
  u16* xyb = p;    p += (size_t)8388608;         // bf16: xb for qkv, then yb

  prep_kernel<<<9216, 256, 0, stream>>>(x, xyb, wqkv, wqkvT, wproj, wprojT);
  qkv_gemm_kernel<<<768, 512, 0, stream>>>(xyb, wqkvT, qb, kb, vtb);
  attn_kernel<<<1024, 256, 0, stream>>>(qb, kb, vtb, xyb);
  proj_gemm_kernel<<<512, 256, 0, stream>>>(xyb, wprojT, out);
}